// Round 1
// baseline (334.558 us; speedup 1.0000x reference)
//
#include <hip/hip_runtime.h>

typedef __attribute__((ext_vector_type(8))) __bf16 bf16x8;
typedef __attribute__((ext_vector_type(4))) float f32x4;

constexpr int BB = 16, NN = 906, CC = 768, HH = 12, MM1 = 513;
constexpr int MTOK = BB * NN;      // 14496 tokens
constexpr int TOKC = MTOK * CC;    // 11132928 elements

#define MFMA16(a, b, c) __builtin_amdgcn_mfma_f32_16x16x32_bf16((a), (b), (c), 0, 0, 0)

__device__ __forceinline__ void glds16(const void* g, void* l) {
  __builtin_amdgcn_global_load_lds(
      (const __attribute__((address_space(1))) void*)g,
      (__attribute__((address_space(3))) void*)l, 16, 0, 0);
}

// ---------------- convert x (fp32 -> bf16) ----------------
__global__ __launch_bounds__(256) void cvt_x_kernel(const float* __restrict__ x,
                                                    __bf16* __restrict__ xb) {
  long i = (long)blockIdx.x * 256 + threadIdx.x;
  const float4* p = (const float4*)x + i * 2;
  float4 a = p[0], b = p[1];
  bf16x8 o;
  o[0] = (__bf16)a.x; o[1] = (__bf16)a.y; o[2] = (__bf16)a.z; o[3] = (__bf16)a.w;
  o[4] = (__bf16)b.x; o[5] = (__bf16)b.y; o[6] = (__bf16)b.z; o[7] = (__bf16)b.w;
  *(bf16x8*)(xb + i * 8) = o;
}

// ---------------- transpose + convert weights: Wt[n][k] = W[k][n] ----------------
__global__ __launch_bounds__(256) void cvt_w_kernel(
    const float* __restrict__ W0, const float* __restrict__ W1,
    const float* __restrict__ W2, const float* __restrict__ W3,
    const float* __restrict__ W4, __bf16* __restrict__ out) {
  __shared__ float t[32][33];
  int z = blockIdx.z;
  const float* src = z == 0 ? W0 : z == 1 ? W1 : z == 2 ? W2 : z == 3 ? W3 : W4;
  __bf16* dst = out + (size_t)z * CC * CC;
  int x0 = blockIdx.x * 32, y0 = blockIdx.y * 32;
  int tx = threadIdx.x & 31, ty = threadIdx.x >> 5;  // ty 0..7
#pragma unroll
  for (int i = 0; i < 4; ++i)
    t[ty + i * 8][tx] = src[(size_t)(y0 + ty + i * 8) * CC + x0 + tx];
  __syncthreads();
#pragma unroll
  for (int i = 0; i < 4; ++i)
    dst[(size_t)(x0 + ty + i * 8) * CC + y0 + tx] = (__bf16)t[tx][ty + i * 8];
}

// ---------------- shared 128x128xK GEMM mainloop (bf16, fp32 acc) ----------------
// A: [M][768] bf16 row-major. Bt: [128 rows][768] bf16 (transposed weight slice).
// XOR-swizzle: LDS tile [128][64], slot(16B) stored at src slot (s ^ (row&7)).
__device__ __forceinline__ void gemm_core(const __bf16* __restrict__ A,
                                          const __bf16* __restrict__ Bt,
                                          __bf16* A_lds, __bf16* B_lds,
                                          int m0, int M, f32x4 acc[4][4]) {
  const int tid = threadIdx.x;
  const int w = tid >> 6, l = tid & 63;
  const int l15 = l & 15, hi = l >> 4;
  const int wr = (w >> 1) * 64, wc = (w & 1) * 64;
  const int srow = l >> 3, sslot = l & 7;

  for (int kt = 0; kt < 12; ++kt) {
#pragma unroll
    for (int rr = 0; rr < 4; ++rr) {
      int row = rr * 32 + w * 8 + srow;
      int arow = m0 + row; arow = arow < M ? arow : M - 1;
      int gco = kt * 64 + ((sslot ^ (row & 7)) * 8);
      glds16(A + (size_t)arow * CC + gco, A_lds + row * 64 + sslot * 8);
      glds16(Bt + (size_t)row * CC + gco, B_lds + row * 64 + sslot * 8);
    }
    __syncthreads();
#pragma unroll
    for (int kks = 0; kks < 2; ++kks) {
      bf16x8 af[4], bfr[4];
#pragma unroll
      for (int mf = 0; mf < 4; ++mf) {
        int rowa = wr + mf * 16 + l15;
        af[mf] = *(const bf16x8*)(A_lds + rowa * 64 + (((kks * 4 + hi) ^ (rowa & 7)) * 8));
      }
#pragma unroll
      for (int nf = 0; nf < 4; ++nf) {
        int rowb = wc + nf * 16 + l15;
        bfr[nf] = *(const bf16x8*)(B_lds + rowb * 64 + (((kks * 4 + hi) ^ (rowb & 7)) * 8));
      }
#pragma unroll
      for (int mf = 0; mf < 4; ++mf)
#pragma unroll
        for (int nf = 0; nf < 4; ++nf)
          acc[mf][nf] = MFMA16(af[mf], bfr[nf], acc[mf][nf]);
    }
    __syncthreads();
  }
}

// ---------------- QKV(+Vc) projection GEMM ----------------
// grid (24, 114): x = n-tile over 4*768 fused cols, y = m-tile over tokens.
// Writes: q,k as [b,h,n,d] bf16 (q pre-scaled by 1/8); v/vc routed into
// VA = [v[:M1];vc[M1:]] and VV = [vc[:M1];v[M1:]], both transposed [b,h,d,n].
__global__ __launch_bounds__(256) void gemm_qkv(
    const __bf16* __restrict__ Xb, const __bf16* __restrict__ WT,
    __bf16* __restrict__ Qb, __bf16* __restrict__ Kb,
    __bf16* __restrict__ VAb, __bf16* __restrict__ VVb) {
  __shared__ alignas(16) __bf16 A_lds[128 * 64];
  __shared__ alignas(16) __bf16 B_lds[128 * 64];
  int nt = blockIdx.x, mt = blockIdx.y;
  int m0 = mt * 128;
  int wi = nt / 6, nc = (nt % 6) * 128;
  const __bf16* bt = WT + (size_t)wi * (CC * CC) + (size_t)nc * CC;
  f32x4 acc[4][4] = {};
  gemm_core(Xb, bt, A_lds, B_lds, m0, MTOK, acc);

  const int tid = threadIdx.x;
  const int w = tid >> 6, l = tid & 63, l15 = l & 15, hi = l >> 4;
  const int wr = (w >> 1) * 64, wc = (w & 1) * 64;
  const float qs = (wi == 0) ? 0.125f : 1.0f;  // fold softmax scale into q
#pragma unroll
  for (int mf = 0; mf < 4; ++mf) {
#pragma unroll
    for (int r = 0; r < 4; ++r) {
      int token = m0 + wr + mf * 16 + hi * 4 + r;
      if (token >= MTOK) continue;
      int b = token / NN, n = token - b * NN;
#pragma unroll
      for (int nf = 0; nf < 4; ++nf) {
        int col = nc + wc + nf * 16 + l15;
        int h = col >> 6, dd = col & 63;
        __bf16 bv = (__bf16)(acc[mf][nf][r] * qs);
        size_t bhd = (size_t)(b * HH + h);
        if (wi == 0)      Qb[(bhd * NN + n) * 64 + dd] = bv;
        else if (wi == 1) Kb[(bhd * NN + n) * 64 + dd] = bv;
        else if (wi == 2) ((n < MM1) ? VAb : VVb)[(bhd * 64 + dd) * NN + n] = bv;
        else              ((n < MM1) ? VVb : VAb)[(bhd * 64 + dd) * NN + n] = bv;
      }
    }
  }
}

// ---------------- flash attention with per-modality V ----------------
// grid (16, 192): x = q-tile (9 mod1 tiles + 7 mod2 tiles), y = b*12+h.
// 4 waves, each owns 16 q rows; K/V tiles 64 keys staged in LDS (swizzled).
__global__ __launch_bounds__(256) void attn_kernel(
    const __bf16* __restrict__ Q, const __bf16* __restrict__ K,
    const __bf16* __restrict__ VA, const __bf16* __restrict__ VV,
    __bf16* __restrict__ AO) {
  __shared__ alignas(16) __bf16 K_lds[64 * 64];
  __shared__ alignas(16) __bf16 V_lds[64 * 64];   // [dd][key]
  __shared__ alignas(16) __bf16 P_lds[4 * 16 * 72];

  const int tid = threadIdx.x;
  const int w = tid >> 6, l = tid & 63;
  const int l15 = l & 15, hi = l >> 4;
  const int bh = blockIdx.y, tile = blockIdx.x;

  int q0, qn; bool mod1;
  if (tile < 9) { q0 = tile * 64; qn = min(64, MM1 - q0); mod1 = true; }
  else { q0 = MM1 + (tile - 9) * 64; qn = min(64, NN - q0); mod1 = false; }

  const __bf16* qp = Q + (size_t)bh * NN * 64;
  const __bf16* kp = K + (size_t)bh * NN * 64;
  const __bf16* vp = (mod1 ? VA : VV) + (size_t)bh * 64 * NN;

  // Q fragments in registers (row = l15 within this wave's 16 rows)
  int qrow = q0 + w * 16 + l15; qrow = qrow < NN ? qrow : NN - 1;
  bf16x8 qf[2];
  qf[0] = *(const bf16x8*)(qp + (size_t)qrow * 64 + hi * 8);
  qf[1] = *(const bf16x8*)(qp + (size_t)qrow * 64 + 32 + hi * 8);

  f32x4 Of[4] = {};
  float m_run[4], l_run[4];
#pragma unroll
  for (int r = 0; r < 4; ++r) { m_run[r] = -1e30f; l_run[r] = 0.f; }

  __bf16* pw = P_lds + w * (16 * 72);

  for (int kt = 0; kt < 15; ++kt) {
    int k0 = kt * 64;
#pragma unroll
    for (int rr = 0; rr < 2; ++rr) {
      int row = rr * 32 + w * 8 + (l >> 3);
      int s = l & 7;
      int krow = k0 + row; krow = krow < NN ? krow : NN - 1;   // dup key 905, masked below
      glds16(kp + (size_t)krow * 64 + ((s ^ (row & 7)) * 8), K_lds + row * 64 + s * 8);
      int vcol = k0 + ((s ^ (row & 7)) * 8);  // may overrun into next ws buffer: finite, masked
      glds16(vp + (size_t)row * NN + vcol, V_lds + row * 64 + s * 8);
    }
    __syncthreads();

    f32x4 sa[4] = {};
#pragma unroll
    for (int kks = 0; kks < 2; ++kks) {
#pragma unroll
      for (int f = 0; f < 4; ++f) {
        int rk = f * 16 + l15;
        bf16x8 kf = *(const bf16x8*)(K_lds + rk * 64 + (((kks * 4 + hi) ^ (rk & 7)) * 8));
        sa[f] = MFMA16(qf[kks], kf, sa[f]);
      }
    }
#pragma unroll
    for (int f = 0; f < 4; ++f) {
      if (k0 + f * 16 + l15 >= NN) {
        sa[f][0] = -1e30f; sa[f][1] = -1e30f; sa[f][2] = -1e30f; sa[f][3] = -1e30f;
      }
    }

    float p[4][4];
#pragma unroll
    for (int r = 0; r < 4; ++r) {
      float rm = fmaxf(fmaxf(sa[0][r], sa[1][r]), fmaxf(sa[2][r], sa[3][r]));
      rm = fmaxf(rm, __shfl_xor(rm, 1));
      rm = fmaxf(rm, __shfl_xor(rm, 2));
      rm = fmaxf(rm, __shfl_xor(rm, 4));
      rm = fmaxf(rm, __shfl_xor(rm, 8));
      float mn = fmaxf(m_run[r], rm);
      float c = __expf(m_run[r] - mn);
      float sum = 0.f;
#pragma unroll
      for (int f = 0; f < 4; ++f) { p[f][r] = __expf(sa[f][r] - mn); sum += p[f][r]; }
      sum += __shfl_xor(sum, 1); sum += __shfl_xor(sum, 2);
      sum += __shfl_xor(sum, 4); sum += __shfl_xor(sum, 8);
      l_run[r] = l_run[r] * c + sum;
      m_run[r] = mn;
#pragma unroll
      for (int fd = 0; fd < 4; ++fd) Of[fd][r] *= c;
    }

    // P round-trip via per-wave LDS: write C-layout, read A-layout
#pragma unroll
    for (int f = 0; f < 4; ++f)
#pragma unroll
      for (int r = 0; r < 4; ++r)
        pw[(hi * 4 + r) * 72 + f * 16 + l15] = (__bf16)p[f][r];
    asm volatile("s_waitcnt lgkmcnt(0)" ::: "memory");
    __builtin_amdgcn_sched_barrier(0);

    bf16x8 pf[2];
    pf[0] = *(const bf16x8*)(pw + l15 * 72 + hi * 8);
    pf[1] = *(const bf16x8*)(pw + l15 * 72 + 32 + hi * 8);
#pragma unroll
    for (int fd = 0; fd < 4; ++fd) {
#pragma unroll
      for (int kks = 0; kks < 2; ++kks) {
        int vrow = fd * 16 + l15;
        bf16x8 vf = *(const bf16x8*)(V_lds + vrow * 64 + (((kks * 4 + hi) ^ (vrow & 7)) * 8));
        Of[fd] = MFMA16(pf[kks], vf, Of[fd]);
      }
    }
    __syncthreads();
  }

  const int bq = bh / HH, hq = bh % HH;
#pragma unroll
  for (int r = 0; r < 4; ++r) {
    int lq = w * 16 + hi * 4 + r;
    if (lq >= qn) continue;
    float inv = 1.0f / l_run[r];
    size_t rowo = ((size_t)(bq * NN + q0 + lq)) * CC + hq * 64;
#pragma unroll
    for (int fd = 0; fd < 4; ++fd)
      AO[rowo + fd * 16 + l15] = (__bf16)(Of[fd][r] * inv);
  }
}

// ---------------- output projection GEMM + bias (fp32 out) ----------------
__global__ __launch_bounds__(256) void gemm_out(
    const __bf16* __restrict__ AO, const __bf16* __restrict__ WPt,
    const float* __restrict__ bias, float* __restrict__ Out) {
  __shared__ alignas(16) __bf16 A_lds[128 * 64];
  __shared__ alignas(16) __bf16 B_lds[128 * 64];
  int nt = blockIdx.x, mt = blockIdx.y;
  int m0 = mt * 128, nc = nt * 128;
  const __bf16* bt = WPt + (size_t)nc * CC;
  f32x4 acc[4][4] = {};
  gemm_core(AO, bt, A_lds, B_lds, m0, MTOK, acc);

  const int tid = threadIdx.x;
  const int w = tid >> 6, l = tid & 63, l15 = l & 15, hi = l >> 4;
  const int wr = (w >> 1) * 64, wc = (w & 1) * 64;
#pragma unroll
  for (int mf = 0; mf < 4; ++mf) {
#pragma unroll
    for (int r = 0; r < 4; ++r) {
      int token = m0 + wr + mf * 16 + hi * 4 + r;
      if (token >= MTOK) continue;
#pragma unroll
      for (int nf = 0; nf < 4; ++nf) {
        int col = nc + wc + nf * 16 + l15;
        Out[(size_t)token * CC + col] = acc[mf][nf][r] + bias[col];
      }
    }
  }
}

extern "C" void kernel_launch(void* const* d_in, const int* in_sizes, int n_in,
                              void* d_out, int out_size, void* d_ws, size_t ws_size,
                              hipStream_t stream) {
  (void)in_sizes; (void)n_in; (void)out_size;
  const float* x   = (const float*)d_in[0];
  const float* Wq  = (const float*)d_in[1];
  const float* Wk  = (const float*)d_in[2];
  const float* Wv  = (const float*)d_in[3];
  const float* Wvc = (const float*)d_in[4];
  const float* Wp  = (const float*)d_in[5];
  const float* bp  = (const float*)d_in[6];
  float* out = (float*)d_out;

  const size_t SZ_TOK = (size_t)TOKC * 2;        // 22,265,856 B per token-tensor
  const size_t SZ_W   = (size_t)CC * CC * 2;     // 1,179,648 B per weight
  const size_t NEED   = SZ_TOK * 6 + SZ_W * 5;   // ~139.5 MB
  if (ws_size < NEED) return;  // graceful fail (visible as absmax error)

  char* ws = (char*)d_ws;
  __bf16* xb  = (__bf16*)ws;
  __bf16* wt  = (__bf16*)(ws + SZ_TOK);
  __bf16* qb  = (__bf16*)(ws + SZ_TOK + 5 * SZ_W);
  __bf16* kb  = qb + TOKC;
  __bf16* vab = kb + TOKC;
  __bf16* vvb = vab + TOKC;
  __bf16* aob = vvb + TOKC;

  cvt_x_kernel<<<TOKC / (256 * 8), 256, 0, stream>>>(x, xb);
  cvt_w_kernel<<<dim3(24, 24, 5), 256, 0, stream>>>(Wq, Wk, Wv, Wvc, Wp, wt);
  gemm_qkv<<<dim3(24, 114), 256, 0, stream>>>(xb, wt, qb, kb, vab, vvb);
  attn_kernel<<<dim3(16, 192), 256, 0, stream>>>(qb, kb, vab, vvb, aob);
  gemm_out<<<dim3(6, 114), 256, 0, stream>>>(aob, wt + 4 * (size_t)(CC * CC), bp, out);
}